// Round 3
// baseline (613.203 us; speedup 1.0000x reference)
//
#include <hip/hip_runtime.h>
#include <math.h>

#define N_PTS (128*128*128)          // 2,097,152 = 8192 * 256 exactly
#define T_HASH 4194304
#define T_MASK (T_HASH - 1)
#define ENTRY_STRIDE 16              // floats per transposed entry (64 B aligned)

__device__ __forceinline__ unsigned hash_idx(int x, int y, int z) {
    return ((unsigned)x ^ ((unsigned)y * 2654435761u)
                        ^ ((unsigned)z * 805459861u)) & T_MASK;
}

// ---------------------------------------------------------------------------
// Kernel 1: transpose (14, T_HASH) -> (T_HASH, 16) padded, all coalesced.
// ---------------------------------------------------------------------------
__global__ void transpose_kernel(const float* __restrict__ table,
                                 float* __restrict__ tt) {
    __shared__ float sh[256 * 17];   // stride 17 (odd) -> conflict-free
    const int t  = threadIdx.x;
    const int i0 = blockIdx.x * 256;

    #pragma unroll
    for (int j = 0; j < 14; ++j)
        sh[t * 17 + j] = table[(size_t)j * T_HASH + i0 + t];   // coalesced read
    sh[t * 17 + 14] = 0.f;
    sh[t * 17 + 15] = 0.f;
    __syncthreads();

    // 256 entries * 64 B = 16 KB contiguous, coalesced float4 stores
    float4* dst = (float4*)(tt + (size_t)i0 * ENTRY_STRIDE);
    #pragma unroll
    for (int k = 0; k < 4; ++k) {
        const int f = t + k * 256;         // float4 slot in [0,1024)
        const int p = f >> 2;              // entry within block
        const int c = f & 3;               // float4 within entry
        const float* s = &sh[p * 17 + c * 4];
        dst[f] = make_float4(s[0], s[1], s[2], s[3]);
    }
}

// ---------------------------------------------------------------------------
// Kernel 2 (fused): one 64 B gather per point; writes RAW g[0:3] to the means
// slot (finalized by fixup), cov/harm/opac with non-temporal stores, and
// accumulates global sum/sumsq for rows 0:3 via block reduce + double atomics.
// Grid covers N_PTS exactly (8192 x 256) -- no bounds check, safe syncthreads.
// Output layout: [0,3N) means | [3N,12N) cov | [12N,15N) harm | [15N,16N) opac
// ---------------------------------------------------------------------------
__global__ void main_fused_kernel(const int* __restrict__ coords,
                                  const float* __restrict__ tt,
                                  const float* __restrict__ far_p,
                                  const int* __restrict__ vs_p,
                                  double* __restrict__ acc,
                                  float* __restrict__ out) {
    const int i = blockIdx.x * 256 + threadIdx.x;

    const float far_s = far_p[0];
    const float vs    = (float)vs_p[0];
    const float two_far_over_vs = 2.f * far_s / vs;

    const int cx = coords[i * 3 + 0];
    const int cy = coords[i * 3 + 1];
    const int cz = coords[i * 3 + 2];
    const unsigned idx = hash_idx(cx, cy, cz);

    const float4* e = (const float4*)(tt + (size_t)idx * ENTRY_STRIDE);
    const float4 f0 = e[0];
    const float4 f1 = e[1];
    const float4 f2 = e[2];
    const float4 f3 = e[3];

    // ---- means slot: raw displacement features (fixup pass finalizes) ----
    out[(size_t)i * 3 + 0] = f0.x;
    out[(size_t)i * 3 + 1] = f0.y;
    out[(size_t)i * 3 + 2] = f0.z;

    // ---- quaternion (g[3:7] = f0.w, f1.x, f1.y, f1.z) -> rotation ----
    float qr = f0.w, qx = f1.x, qy = f1.y, qz = f1.z;
    const float qinv = 1.f / sqrtf(qr * qr + qx * qx + qy * qy + qz * qz);
    qr *= qinv; qx *= qinv; qy *= qinv; qz *= qinv;

    float R[3][3];
    R[0][0] = 1.f - 2.f * (qy * qy + qz * qz);
    R[0][1] = 2.f * (qx * qy - qr * qz);
    R[0][2] = 2.f * (qx * qz + qr * qy);
    R[1][0] = 2.f * (qx * qy + qr * qz);
    R[1][1] = 1.f - 2.f * (qx * qx + qz * qz);
    R[1][2] = 2.f * (qy * qz - qr * qx);
    R[2][0] = 2.f * (qx * qz - qr * qy);
    R[2][1] = 2.f * (qy * qz + qr * qx);
    R[2][2] = 1.f - 2.f * (qx * qx + qy * qy);

    // ---- scales = sigmoid(g[7:10]) * 2far/vs  (g[7]=f1.w, g[8]=f2.x, g[9]=f2.y)
    float sc[3];
    sc[0] = two_far_over_vs / (1.f + expf(-f1.w));
    sc[1] = two_far_over_vs / (1.f + expf(-f2.x));
    sc[2] = two_far_over_vs / (1.f + expf(-f2.y));

    // ---- cov = (R diag(sc)) (R diag(sc))^T, non-temporal ----
    float* covp = out + (size_t)3 * N_PTS + (size_t)i * 9;
    #pragma unroll
    for (int r = 0; r < 3; ++r) {
        #pragma unroll
        for (int c = 0; c < 3; ++c) {
            float a = 0.f;
            #pragma unroll
            for (int j = 0; j < 3; ++j)
                a += (R[r][j] * sc[j]) * (R[c][j] * sc[j]);
            __builtin_nontemporal_store(a, covp + r * 3 + c);
        }
    }

    // ---- harmonics (g[10:13] = f2.z, f2.w, f3.x), non-temporal ----
    float* harp = out + (size_t)12 * N_PTS + (size_t)i * 3;
    __builtin_nontemporal_store(f2.z, harp + 0);
    __builtin_nontemporal_store(f2.w, harp + 1);
    __builtin_nontemporal_store(f3.x, harp + 2);

    // ---- opacity = sigmoid(g[13] - 4)  (g[13] = f3.y), non-temporal ----
    __builtin_nontemporal_store(1.f / (1.f + expf(-(f3.y - 4.f))),
                                out + (size_t)15 * N_PTS + i);

    // ---- fused global reduction over g[0:3] ----
    float s  = f0.x + f0.y + f0.z;
    float ss = f0.x * f0.x + f0.y * f0.y + f0.z * f0.z;
    #pragma unroll
    for (int off = 32; off > 0; off >>= 1) {
        s  += __shfl_down(s, off, 64);
        ss += __shfl_down(ss, off, 64);
    }
    __shared__ float sh_s[4], sh_ss[4];
    const int lane = threadIdx.x & 63;
    const int wid  = threadIdx.x >> 6;
    if (lane == 0) { sh_s[wid] = s; sh_ss[wid] = ss; }
    __syncthreads();
    if (threadIdx.x == 0) {
        float ts = 0.f, tss = 0.f;
        #pragma unroll
        for (int w = 0; w < 4; ++w) { ts += sh_s[w]; tss += sh_ss[w]; }
        atomicAdd(&acc[0], (double)ts);
        atomicAdd(&acc[1], (double)tss);
    }
}

// ---------------------------------------------------------------------------
// Kernel 3: finalize means — streaming affine fixup using global mean/std.
// ---------------------------------------------------------------------------
__global__ void means_fixup_kernel(const int* __restrict__ coords,
                                   const float* __restrict__ cam,
                                   const float* __restrict__ far_p,
                                   const int* __restrict__ vs_p,
                                   const double* __restrict__ acc,
                                   float* __restrict__ out) {
    const int i = blockIdx.x * 256 + threadIdx.x;

    const float far_s = far_p[0];
    const float vs    = (float)vs_p[0];

    const double n      = 3.0 * (double)N_PTS;
    const double sum    = acc[0];
    const double sumsq  = acc[1];
    const double mean_d = sum / n;
    const double var_d  = (sumsq - sum * sum / n) / (n - 1.0);
    const float mean    = (float)mean_d;
    const float a       = (float)(1.0 / sqrt(var_d)) * (2.f * far_s / vs / 6.f);

    const int cx = coords[i * 3 + 0];
    const int cy = coords[i * 3 + 1];
    const int cz = coords[i * 3 + 2];
    const float c_f[3] = { (float)cx, (float)cy, (float)cz };

    float m[3];
    #pragma unroll
    for (int k = 0; k < 3; ++k)
        m[k] = out[(size_t)i * 3 + k];

    #pragma unroll
    for (int k = 0; k < 3; ++k) {
        const float vc = c_f[k] / vs * 2.f * far_s - far_s + cam[k] + far_s / vs;
        out[(size_t)i * 3 + k] = (m[k] - mean) * a + vc;
    }
}

extern "C" void kernel_launch(void* const* d_in, const int* in_sizes, int n_in,
                              void* d_out, int out_size, void* d_ws, size_t ws_size,
                              hipStream_t stream) {
    const int*   coords = (const int*)d_in[0];
    const float* table  = (const float*)d_in[1];
    const float* cam    = (const float*)d_in[2];
    const float* far_p  = (const float*)d_in[3];
    const int*   vs_p   = (const int*)d_in[4];
    float*       out    = (float*)d_out;

    double* acc = (double*)d_ws;
    float*  tt  = (float*)((char*)d_ws + 256);

    hipMemsetAsync(d_ws, 0, 2 * sizeof(double), stream);

    transpose_kernel<<<T_HASH / 256, 256, 0, stream>>>(table, tt);
    main_fused_kernel<<<N_PTS / 256, 256, 0, stream>>>(coords, tt, far_p, vs_p,
                                                       acc, out);
    means_fixup_kernel<<<N_PTS / 256, 256, 0, stream>>>(coords, cam, far_p, vs_p,
                                                        acc, out);
}